// Round 4
// baseline (274.955 us; speedup 1.0000x reference)
//
#include <hip/hip_runtime.h>

// DerivativeNet direction='x' — one wave per (b,y) row, no LDS, no barriers,
// ballot-based mask scan (no dependent shfl chain), all 12 loads in flight.
// B=16, C=2, H=1024, W=1024 fp32. Lane l owns chunks c=0..3, elements
// w = c*256 + l*4 + j (float4). Min traffic 320 MiB -> memory-bound.

#define WDIM 1024

typedef float v4f __attribute__((ext_vector_type(4)));  // native vec for NT store

__global__ __launch_bounds__(256, 4) void deriv_x_kernel(
    const float* __restrict__ u,
    const float* __restrict__ mask,
    float* __restrict__ out)
{
    const int wave = threadIdx.x >> 6;
    const int lane = threadIdx.x & 63;
    const int row  = blockIdx.x * 4 + wave;   // b*1024 + y
    const int b    = row >> 10;
    const int y    = row & 1023;

    const size_t mrow = (size_t)row * WDIM;                   // mask[b,0,y,:]
    const size_t u0r  = ((size_t)(b * 2) * WDIM + y) * WDIM;  // u[b,0,y,:]
    const size_t u1r  = u0r + (size_t)WDIM * WDIM;            // u[b,1,y,:]

    // ---- issue ALL 12 loads before any consumer (mask last: first consumed,
    // so its wait covers everything -> one latency exposure, max MLP) ----
    float4 a[4], d[4], mv[4];
    #pragma unroll
    for (int c = 0; c < 4; ++c)
        a[c] = *(const float4*)(u + u0r + c * 256 + lane * 4);
    #pragma unroll
    for (int c = 0; c < 4; ++c)
        d[c] = *(const float4*)(u + u1r + c * 256 + lane * 4);
    #pragma unroll
    for (int c = 0; c < 4; ++c)
        mv[c] = *(const float4*)(mask + mrow + c * 256 + lane * 4);

    // ---- ballots: bit l of bj[c] = mask at w = c*256 + l*4 + j ----
    unsigned long long b0[4], b1[4], b2[4], b3[4];
    #pragma unroll
    for (int c = 0; c < 4; ++c) {
        b0[c] = __ballot(mv[c].x != 0.0f);
        b1[c] = __ballot(mv[c].y != 0.0f);
        b2[c] = __ballot(mv[c].z != 0.0f);
        b3[c] = __ballot(mv[c].w != 0.0f);
    }

    // ---- wave-uniform chunk totals -> carries (scalar unit) ----
    int carry[4];
    int runv = 0;
    #pragma unroll
    for (int c = 0; c < 4; ++c) {
        carry[c] = runv;
        runv += __popcll(b0[c]) + __popcll(b1[c]) + __popcll(b2[c]) + __popcll(b3[c]);
    }
    const int total = runv;   // row total (== max of cumsum when > 0)

    const unsigned long long below = (1ull << lane) - 1ull;  // lanes < me
    const float inv2h = 50.0f;   // 1/(2h), h = 0.01
    const float invh  = 100.0f;  // 1/h

    #pragma unroll
    for (int c = 0; c < 4; ++c) {
        const int i0 = (int)mv[c].x, i1 = (int)mv[c].y;
        const int i2 = (int)mv[c].z, i3 = (int)mv[c].w;

        // exclusive prefix at this lane's chunk slot: independent popcounts
        const int pre = carry[c]
            + __popcll(b0[c] & below) + __popcll(b1[c] & below)
            + __popcll(b2[c] & below) + __popcll(b3[c] & below);
        const int cs0 = pre + i0, cs1 = cs0 + i1, cs2 = cs1 + i2, cs3 = cs2 + i3;

        // mask halos from ballot words (zero-padded at row ends), no shfl:
        // left of (l, j=0) = bit l-1 of b3 (chunk carry via <<1)
        // right of (l, j=3) = bit l+1 of b0 (chunk carry via >>1)
        const unsigned long long mlw =
            (b3[c] << 1) | (c > 0 ? (b3[c - 1] >> 63) : 0ull);
        const unsigned long long mrw =
            (b0[c] >> 1) | (c < 3 ? (b0[c + 1] << 63) : 0ull);
        const int ml = (int)((mlw >> lane) & 1ull);
        const int mr = (int)((mrw >> lane) & 1ull);

        // eroded: 3-box == 3
        const float er0 = (ml + i0 + i1 == 3) ? 1.f : 0.f;
        const float er1 = (i0 + i1 + i2 == 3) ? 1.f : 0.f;
        const float er2 = (i1 + i2 + i3 == 3) ? 1.f : 0.f;
        const float er3 = (i2 + i3 + mr == 3) ? 1.f : 0.f;

        // edge1: cs == 1 (no mask AND, per reference); edge2: mask && cs == total
        const float e10 = (cs0 == 1) ? 1.f : 0.f;
        const float e11 = (cs1 == 1) ? 1.f : 0.f;
        const float e12 = (cs2 == 1) ? 1.f : 0.f;
        const float e13 = (cs3 == 1) ? 1.f : 0.f;
        const float e20 = (i0 && cs0 == total) ? 1.f : 0.f;
        const float e21 = (i1 && cs1 == total) ? 1.f : 0.f;
        const float e22 = (i2 && cs2 == total) ? 1.f : 0.f;
        const float e23 = (i3 && cs3 == total) ? 1.f : 0.f;

        const int off = c * 256 + lane * 4;

        // u halos: single ring-rotate shfl each (src lane 63/0 publishes the
        // cross-chunk value; it is only consumed by the wrap-around dest).
#define DO_CH(ARR, ROFF)                                                            \
        {                                                                           \
            const float4 V = ARR[c];                                                \
            const float pubL = (lane == 63) ? (c > 0 ? ARR[c - 1].w : 0.f) : V.w;   \
            const float pubR = (lane == 0)  ? (c < 3 ? ARR[c + 1].x : 0.f) : V.x;   \
            const float ul = __shfl(pubL, (lane + 63) & 63, 64);                    \
            const float ur = __shfl(pubR, (lane + 1) & 63, 64);                     \
            const float l0 = ul,  r0 = V.y;                                         \
            const float l1 = V.x, r1 = V.z;                                         \
            const float l2 = V.y, r2 = V.w;                                         \
            const float l3 = V.z, r3 = ur;                                          \
            v4f o;                                                                  \
            o.x = er0*((r0-l0)*inv2h) + e10*((r0-V.x)*invh) + e20*((V.x-l0)*invh);  \
            o.y = er1*((r1-l1)*inv2h) + e11*((r1-V.y)*invh) + e21*((V.y-l1)*invh);  \
            o.z = er2*((r2-l2)*inv2h) + e12*((r2-V.z)*invh) + e22*((V.z-l2)*invh);  \
            o.w = er3*((r3-l3)*inv2h) + e13*((r3-V.w)*invh) + e23*((V.w-l3)*invh);  \
            __builtin_nontemporal_store(o, (v4f*)(out + ROFF + off));               \
        }

        DO_CH(a, u0r)
        DO_CH(d, u1r)
#undef DO_CH
    }
}

extern "C" void kernel_launch(void* const* d_in, const int* in_sizes, int n_in,
                              void* d_out, int out_size, void* d_ws, size_t ws_size,
                              hipStream_t stream) {
    const float* u    = (const float*)d_in[0];
    const float* mask = (const float*)d_in[1];
    float* out        = (float*)d_out;
    // 16384 rows, one wave per row, 4 waves (rows) per 256-thread block
    deriv_x_kernel<<<dim3(16 * 1024 / 4), dim3(256), 0, stream>>>(u, mask, out);
}

// Round 5
// 268.071 us; speedup vs baseline: 1.0257x; 1.0257x over previous
//
#include <hip/hip_runtime.h>

// DerivativeNet direction='x', two-phase:
//   K1: mask row -> 3-bit per-element code (er, e1, e2) via ballot scan (wave/row)
//   K2: pure streaming stencil: out = er*((r-l)*50) + e1*((r-m)*100) + e2*((m-l)*100)
//       one thread per float4, fully independent (copy-shaped, max latency tolerance)
// B=16, C=2, H=1024, W=1024 fp32.

#define WDIM 1024

typedef float v4f __attribute__((ext_vector_type(4)));

// ---------------- Kernel 1: mask -> codes (1 byte/element) ----------------
__global__ __launch_bounds__(256) void mask_codes_kernel(
    const float* __restrict__ mask, unsigned int* __restrict__ codes)
{
    const int wave = threadIdx.x >> 6;
    const int lane = threadIdx.x & 63;
    const int row  = blockIdx.x * 4 + wave;          // b*1024 + y
    const size_t mrow = (size_t)row * WDIM;

    float4 mv[4];
    #pragma unroll
    for (int c = 0; c < 4; ++c)
        mv[c] = *(const float4*)(mask + mrow + c * 256 + lane * 4);

    // ballots: bit l of bj[c] = mask at w = c*256 + l*4 + j
    unsigned long long b0[4], b1[4], b2[4], b3[4];
    #pragma unroll
    for (int c = 0; c < 4; ++c) {
        b0[c] = __ballot(mv[c].x != 0.0f);
        b1[c] = __ballot(mv[c].y != 0.0f);
        b2[c] = __ballot(mv[c].z != 0.0f);
        b3[c] = __ballot(mv[c].w != 0.0f);
    }

    int carry[4]; int runv = 0;
    #pragma unroll
    for (int c = 0; c < 4; ++c) {
        carry[c] = runv;
        runv += __popcll(b0[c]) + __popcll(b1[c]) + __popcll(b2[c]) + __popcll(b3[c]);
    }
    const int total = runv;
    const unsigned long long below = (1ull << lane) - 1ull;

    #pragma unroll
    for (int c = 0; c < 4; ++c) {
        const int i0 = (int)mv[c].x, i1 = (int)mv[c].y;
        const int i2 = (int)mv[c].z, i3 = (int)mv[c].w;

        const int pre = carry[c]
            + __popcll(b0[c] & below) + __popcll(b1[c] & below)
            + __popcll(b2[c] & below) + __popcll(b3[c] & below);
        const int cs0 = pre + i0, cs1 = cs0 + i1, cs2 = cs1 + i2, cs3 = cs2 + i3;

        // mask halos via ballot-word shifts (zero-padded at row ends)
        const unsigned long long mlw = (b3[c] << 1) | (c > 0 ? (b3[c - 1] >> 63) : 0ull);
        const unsigned long long mrw = (b0[c] >> 1) | (c < 3 ? (b0[c + 1] << 63) : 0ull);
        const int ml = (int)((mlw >> lane) & 1ull);
        const int mr = (int)((mrw >> lane) & 1ull);

        // code bits: bit0 = eroded (3-box==3), bit1 = (cs==1), bit2 = (mask && cs==total)
        const unsigned cb0 = (unsigned)(ml + i0 + i1 == 3) | ((unsigned)(cs0 == 1) << 1)
                           | ((unsigned)(i0 && cs0 == total) << 2);
        const unsigned cb1 = (unsigned)(i0 + i1 + i2 == 3) | ((unsigned)(cs1 == 1) << 1)
                           | ((unsigned)(i1 && cs1 == total) << 2);
        const unsigned cb2 = (unsigned)(i1 + i2 + i3 == 3) | ((unsigned)(cs2 == 1) << 1)
                           | ((unsigned)(i2 && cs2 == total) << 2);
        const unsigned cb3 = (unsigned)(i2 + i3 + mr == 3) | ((unsigned)(cs3 == 1) << 1)
                           | ((unsigned)(i3 && cs3 == total) << 2);

        codes[(size_t)row * 256 + c * 64 + lane] =
            cb0 | (cb1 << 8) | (cb2 << 16) | (cb3 << 24);
    }
}

// ---------------- Kernel 2: streaming stencil, independent threads ----------------
__global__ __launch_bounds__(256) void stencil_kernel(
    const float* __restrict__ u, const unsigned int* __restrict__ codes,
    float* __restrict__ out)
{
    const int g  = blockIdx.x * 256 + threadIdx.x;   // 0 .. 8388607
    const int w4 = g & 255;                          // float4 index within row
    const int r  = g >> 8;                           // 0..32767 over (b, ch, y)
    const size_t uoff = ((size_t)r << 10) + (w4 << 2);

    // code row = b*1024 + y (mask has no channel dim); r = ((b*2)+ch)*1024 + y
    const int crow = ((r >> 11) << 10) | (r & 1023);
    const unsigned cw = codes[((size_t)crow << 8) + w4];

    const float4 v = *(const float4*)(u + uoff);
    float ul = 0.0f, ur = 0.0f;
    if (w4 != 0)   ul = u[uoff - 1];   // exec-masked: no OOB speculation
    if (w4 != 255) ur = u[uoff + 4];

    v4f o;
#define ELEM(J, L, M, R)                                                     \
    {                                                                        \
        const unsigned cb = (cw >> (8 * (J))) & 7u;                          \
        const float fer = (float)(cb & 1u);                                  \
        const float fe1 = (float)((cb >> 1) & 1u);                           \
        const float fe2 = (float)(cb >> 2);                                  \
        o[J] = fer * (((R) - (L)) * 50.0f)                                   \
             + fe1 * (((R) - (M)) * 100.0f)                                  \
             + fe2 * (((M) - (L)) * 100.0f);                                 \
    }
    ELEM(0, ul,  v.x, v.y)
    ELEM(1, v.x, v.y, v.z)
    ELEM(2, v.y, v.z, v.w)
    ELEM(3, v.z, v.w, ur)
#undef ELEM

    __builtin_nontemporal_store(o, (v4f*)(out + uoff));
}

// ---------------- Fallback (ws too small): R4 fused kernel (verified) ----------------
__global__ __launch_bounds__(256, 4) void deriv_x_fused(
    const float* __restrict__ u, const float* __restrict__ mask,
    float* __restrict__ out)
{
    const int wave = threadIdx.x >> 6;
    const int lane = threadIdx.x & 63;
    const int row  = blockIdx.x * 4 + wave;
    const int b    = row >> 10;
    const int y    = row & 1023;

    const size_t mrow = (size_t)row * WDIM;
    const size_t u0r  = ((size_t)(b * 2) * WDIM + y) * WDIM;
    const size_t u1r  = u0r + (size_t)WDIM * WDIM;

    float4 a[4], d[4], mv[4];
    #pragma unroll
    for (int c = 0; c < 4; ++c) a[c] = *(const float4*)(u + u0r + c * 256 + lane * 4);
    #pragma unroll
    for (int c = 0; c < 4; ++c) d[c] = *(const float4*)(u + u1r + c * 256 + lane * 4);
    #pragma unroll
    for (int c = 0; c < 4; ++c) mv[c] = *(const float4*)(mask + mrow + c * 256 + lane * 4);

    unsigned long long b0[4], b1[4], b2[4], b3[4];
    #pragma unroll
    for (int c = 0; c < 4; ++c) {
        b0[c] = __ballot(mv[c].x != 0.0f);
        b1[c] = __ballot(mv[c].y != 0.0f);
        b2[c] = __ballot(mv[c].z != 0.0f);
        b3[c] = __ballot(mv[c].w != 0.0f);
    }
    int carry[4]; int runv = 0;
    #pragma unroll
    for (int c = 0; c < 4; ++c) {
        carry[c] = runv;
        runv += __popcll(b0[c]) + __popcll(b1[c]) + __popcll(b2[c]) + __popcll(b3[c]);
    }
    const int total = runv;
    const unsigned long long below = (1ull << lane) - 1ull;

    #pragma unroll
    for (int c = 0; c < 4; ++c) {
        const int i0 = (int)mv[c].x, i1 = (int)mv[c].y;
        const int i2 = (int)mv[c].z, i3 = (int)mv[c].w;
        const int pre = carry[c]
            + __popcll(b0[c] & below) + __popcll(b1[c] & below)
            + __popcll(b2[c] & below) + __popcll(b3[c] & below);
        const int cs0 = pre + i0, cs1 = cs0 + i1, cs2 = cs1 + i2, cs3 = cs2 + i3;
        const unsigned long long mlw = (b3[c] << 1) | (c > 0 ? (b3[c-1] >> 63) : 0ull);
        const unsigned long long mrw = (b0[c] >> 1) | (c < 3 ? (b0[c+1] << 63) : 0ull);
        const int ml = (int)((mlw >> lane) & 1ull);
        const int mr = (int)((mrw >> lane) & 1ull);
        const float er0 = (ml+i0+i1 == 3) ? 1.f : 0.f;
        const float er1 = (i0+i1+i2 == 3) ? 1.f : 0.f;
        const float er2 = (i1+i2+i3 == 3) ? 1.f : 0.f;
        const float er3 = (i2+i3+mr == 3) ? 1.f : 0.f;
        const float e10 = (cs0 == 1) ? 1.f : 0.f;
        const float e11 = (cs1 == 1) ? 1.f : 0.f;
        const float e12 = (cs2 == 1) ? 1.f : 0.f;
        const float e13 = (cs3 == 1) ? 1.f : 0.f;
        const float e20 = (i0 && cs0 == total) ? 1.f : 0.f;
        const float e21 = (i1 && cs1 == total) ? 1.f : 0.f;
        const float e22 = (i2 && cs2 == total) ? 1.f : 0.f;
        const float e23 = (i3 && cs3 == total) ? 1.f : 0.f;
        const int off = c * 256 + lane * 4;
#define DO_CH(ARR, ROFF)                                                            \
        {                                                                           \
            const float4 V = ARR[c];                                                \
            const float pubL = (lane == 63) ? (c > 0 ? ARR[c-1].w : 0.f) : V.w;     \
            const float pubR = (lane == 0)  ? (c < 3 ? ARR[c+1].x : 0.f) : V.x;     \
            const float ulx = __shfl(pubL, (lane + 63) & 63, 64);                   \
            const float urx = __shfl(pubR, (lane + 1) & 63, 64);                    \
            const float l0 = ulx, r0 = V.y;                                         \
            const float l1 = V.x, r1 = V.z;                                         \
            const float l2 = V.y, r2 = V.w;                                         \
            const float l3 = V.z, r3 = urx;                                         \
            v4f o;                                                                  \
            o.x = er0*((r0-l0)*50.f) + e10*((r0-V.x)*100.f) + e20*((V.x-l0)*100.f); \
            o.y = er1*((r1-l1)*50.f) + e11*((r1-V.y)*100.f) + e21*((V.y-l1)*100.f); \
            o.z = er2*((r2-l2)*50.f) + e12*((r2-V.z)*100.f) + e22*((V.z-l2)*100.f); \
            o.w = er3*((r3-l3)*50.f) + e13*((r3-V.w)*100.f) + e23*((V.w-l3)*100.f); \
            __builtin_nontemporal_store(o, (v4f*)(out + ROFF + off));               \
        }
        DO_CH(a, u0r)
        DO_CH(d, u1r)
#undef DO_CH
    }
}

extern "C" void kernel_launch(void* const* d_in, const int* in_sizes, int n_in,
                              void* d_out, int out_size, void* d_ws, size_t ws_size,
                              hipStream_t stream) {
    const float* u    = (const float*)d_in[0];
    const float* mask = (const float*)d_in[1];
    float* out        = (float*)d_out;

    const size_t codes_bytes = (size_t)16 * 1024 * 1024;  // 1 B/elem, [16,1024,1024]
    if (ws_size >= codes_bytes) {
        unsigned int* codes = (unsigned int*)d_ws;
        // K1: 16384 rows, wave per row, 4 rows per block
        mask_codes_kernel<<<dim3(16 * 1024 / 4), dim3(256), 0, stream>>>(mask, codes);
        // K2: 33.55M elements / 4 per thread / 256 per block
        stencil_kernel<<<dim3(32768), dim3(256), 0, stream>>>(u, codes, out);
    } else {
        deriv_x_fused<<<dim3(16 * 1024 / 4), dim3(256), 0, stream>>>(u, mask, out);
    }
}